// Round 9
// baseline (386.659 us; speedup 1.0000x reference)
//
#include <hip/hip_runtime.h>
#include <hip/hip_bf16.h>
#include <hip/hip_fp16.h>

typedef unsigned short u16;
typedef unsigned int u32;
typedef __attribute__((ext_vector_type(8))) _Float16 f16x8;
typedef __attribute__((ext_vector_type(4))) float f32x4;

#define NEG 0.2f

__device__ __forceinline__ float bf2f(u16 u) {
    return __uint_as_float(((u32)u) << 16);
}
__device__ __forceinline__ u16 f2b(float f) {   // round-to-nearest-even f32->bf16
    u32 u = __float_as_uint(f);
    u32 r = (u + 0x7FFF + ((u >> 16) & 1)) >> 16;
    return (u16)r;
}
__device__ __forceinline__ u16 f2h(float f) {   // f32 -> f16 bits
    return __half_as_ushort(__float2half(f));
}
__device__ __forceinline__ float h2f(u16 u) {
    return __half2float(__ushort_as_half(u));
}
__device__ __forceinline__ float sigm(float x) {
    return 1.0f / (1.0f + __expf(-x));
}
__device__ __forceinline__ float ldin(const void* p, int idx, int flag) {
    if (flag) return ((const float*)p)[idx];
    return bf2f(((const u16*)p)[idx]);
}
__device__ __forceinline__ u16 ldin_h(const void* p, int idx, int flag) {  // -> f16 bits
    if (flag) return f2h(((const float*)p)[idx]);
    return f2h(bf2f(((const u16*)p)[idx]));
}

// ---------------- ws layout (bytes) ----------------
// flag    u32                        @ 0          (64)
// wiA     f16 [12][9][2][64][8]      @ 64         (221184)  i2h A-frags
// wfA     f16 [2][25][4][64][8]      @ 221248     (204800)  flowfeat A-frags
// wlA     f16 [2][25][64][8]         @ 426048     (51200)   flows A-frags
// wretA   f16 [12][26][64][8]        @ 477248     (319488)  ret A-frags
// biases  f32 [474]                  @ 796736     (2048)
// xph     f16 [8][96][96][128]       @ 798784     (18874368)  NHWC x||prev_h
// (i2hT region unused since R8 fusion)
// fT      f16 [8][96][96][32]        @ 47984704   (4718592)
// flows   f32 [8][26][96][96]        @ 52703296   (7667712)
// total: 60371008

#define WS_NEED 60371008u

// ---------------- K-1: dtype detect ----------------
__global__ void kdetect(const u16* __restrict__ x, u32* __restrict__ flag)
{
    __shared__ u32 mx[256];
    int t = threadIdx.x;
    u32 m = 0;
    for (int i = t; i < 8192; i += 256) {
        u32 e = ((u32)x[i] >> 7) & 0xFF;
        m = m > e ? m : e;
    }
    mx[t] = m;
    __syncthreads();
    for (int s = 128; s > 0; s >>= 1) {
        if (t < s) mx[t] = mx[t] > mx[t + s] ? mx[t] : mx[t + s];
        __syncthreads();
    }
    if (t == 0) flag[0] = (mx[0] > 0xC0) ? 1u : 0u;
}

// ---------------- K0a: weight repack -> MFMA A-fragments (f16) ----------------
__global__ void kprep(const void* __restrict__ w_i2h, const void* __restrict__ w_i2f,
                      const void* __restrict__ w_h2f, const void* __restrict__ w_fl,
                      const void* __restrict__ w_ret,
                      const void* __restrict__ b_i2h, const void* __restrict__ b_i2f,
                      const void* __restrict__ b_h2f, const void* __restrict__ b_fl,
                      const void* __restrict__ b_ret,
                      u16* __restrict__ wiA, u16* __restrict__ wfA,
                      u16* __restrict__ wlA, u16* __restrict__ wretA,
                      float* __restrict__ biases, const u32* __restrict__ flag)
{
    int flg = (int)flag[0];
    int i = blockIdx.x * 256 + threadIdx.x;
    // A-frag pattern: A[m=lane&15][k=(lane>>4)*8+j]  (validated R4)
    if (i < 110592) {                 // wiA [mt12][tap9][cib2][lane][j]
        int j = i & 7; int lane = (i >> 3) & 63; int rest = i >> 9;
        int cib = rest & 1; int rest2 = rest >> 1;
        int tap = rest2 % 9; int mt = rest2 / 9;
        int oc = mt * 16 + (lane & 15);
        int ci = cib * 32 + ((lane >> 4) << 3) + j;
        wiA[i] = ldin_h(w_i2h, (oc * 64 + ci) * 9 + tap, flg);
    }
    if (i < 102400) {                 // wfA [mt2][tap25][cib4][lane][j]
        int j = i & 7; int lane = (i >> 3) & 63; int rest = i >> 9;
        int cib = rest & 3; int rest2 = rest >> 2;
        int tap = rest2 % 25; int mt = rest2 / 25;
        int oc = mt * 16 + (lane & 15);
        int cip = cib * 32 + ((lane >> 4) << 3) + j;
        wfA[i] = (cip < 64) ? ldin_h(w_i2f, (oc * 64 + cip) * 25 + tap, flg)
                            : ldin_h(w_h2f, (oc * 64 + cip - 64) * 25 + tap, flg);
    }
    if (i < 25600) {                  // wlA [mt2][tap25][lane][j], oc>=26 -> 0
        int j = i & 7; int lane = (i >> 3) & 63; int rest = i >> 9;
        int tap = rest % 25; int mt = rest / 25;
        int oc = mt * 16 + (lane & 15);
        int ci = ((lane >> 4) << 3) + j;
        wlA[i] = (oc < 26) ? ldin_h(w_fl, (oc * 32 + ci) * 25 + tap, flg) : (u16)0;
    }
    if (i < 159744) {                 // wretA [mt12][ks26][lane][j]
        int j = i & 7; int l = (i >> 3) & 63; int rest = i >> 9;
        int ks = rest % 26; int mt = rest / 26;
        int o = mt * 16 + (l & 15);
        int k = ks * 32 + ((l >> 4) << 3) + j;
        wretA[i] = ldin_h(w_ret, o * 832 + k, flg);
    }
    if (i < 474) {
        float v;
        if (i < 192)      v = ldin(b_i2h, i, flg);
        else if (i < 224) v = ldin(b_i2f, i - 192, flg);
        else if (i < 256) v = ldin(b_h2f, i - 224, flg);
        else if (i < 282) v = ldin(b_fl, i - 256, flg);
        else              v = ldin(b_ret, i - 282, flg);
        biases[i] = v;
    }
}

// ---------------- K0b: x, prev_h (NCHW) -> xph NHWC f16 [B][H][W][128] ------
__global__ __launch_bounds__(256) void kxph(const void* __restrict__ x,
        const void* __restrict__ ph, u16* __restrict__ xph,
        const u32* __restrict__ flag)
{
    __shared__ __align__(16) u16 tile[64 * 104];
    int flg = (int)flag[0];
    int h = blockIdx.x, b = blockIdx.y;
    int t = threadIdx.x;
#pragma unroll 1
    for (int s = 0; s < 2; s++) {
        const void* src = s ? ph : x;
#pragma unroll 1
        for (int i = t; i < 768; i += 256) {      // 64 c x 12 w-chunks of 8
            int wc = i % 12, c = i / 12;
            int base = ((b * 64 + c) * 96 + h) * 96 + wc * 8;
            u16 r[8];
            if (flg) {
                const float* sp = (const float*)src + base;
                float4 f0 = *(const float4*)sp;
                float4 f1 = *(const float4*)(sp + 4);
                r[0] = f2h(f0.x); r[1] = f2h(f0.y); r[2] = f2h(f0.z); r[3] = f2h(f0.w);
                r[4] = f2h(f1.x); r[5] = f2h(f1.y); r[6] = f2h(f1.z); r[7] = f2h(f1.w);
            } else {
                const u16* sp = (const u16*)src + base;
                uint4 u = *(const uint4*)sp;
                r[0] = f2h(bf2f((u16)(u.x & 0xFFFF))); r[1] = f2h(bf2f((u16)(u.x >> 16)));
                r[2] = f2h(bf2f((u16)(u.y & 0xFFFF))); r[3] = f2h(bf2f((u16)(u.y >> 16)));
                r[4] = f2h(bf2f((u16)(u.z & 0xFFFF))); r[5] = f2h(bf2f((u16)(u.z >> 16)));
                r[6] = f2h(bf2f((u16)(u.w & 0xFFFF))); r[7] = f2h(bf2f((u16)(u.w >> 16)));
            }
            uint4 o;
            o.x = r[0] | ((u32)r[1] << 16); o.y = r[2] | ((u32)r[3] << 16);
            o.z = r[4] | ((u32)r[5] << 16); o.w = r[6] | ((u32)r[7] << 16);
            *(uint4*)&tile[c * 104 + wc * 8] = o;
        }
        __syncthreads();
#pragma unroll 1
        for (int i = t; i < 768; i += 256) {      // 96 w x 8 c-groups of 8
            int cg = i & 7, w = i >> 3;
            u16 v[8];
#pragma unroll
            for (int k = 0; k < 8; k++) v[k] = tile[(cg * 8 + k) * 104 + w];
            uint4 o;
            o.x = v[0] | ((u32)v[1] << 16); o.y = v[2] | ((u32)v[3] << 16);
            o.z = v[4] | ((u32)v[5] << 16); o.w = v[6] | ((u32)v[7] << 16);
            *(uint4*)&xph[(((b * 96 + h) * 96 + w) << 7) + s * 64 + cg * 8] = o;
        }
        __syncthreads();
    }
}

// ---------------- K2: flowfeat 5x5 conv (128 -> 32) via MFMA, out NHWC f16 --
__global__ __launch_bounds__(256) void k_flowfeat(const u16* __restrict__ xph,
        const u16* __restrict__ wfA, const float* __restrict__ biases,
        u16* __restrict__ fT)
{
    __shared__ __align__(16) u16 xl[8 * 20 * 136];   // 43520 B, x-stride 136
    int lin = blockIdx.x;            // 0..1151
    int b = lin & 7;
    int r = lin >> 3;                // 0..143
    int x0 = (r % 6) * 16, y0 = (r / 6) * 4;
    int t = threadIdx.x, lane = t & 63, wv = t >> 6;
    int n = lane & 15, quad = lane >> 4;

    for (int i = t; i < 2560; i += 256) {   // 160 pos x 16 chunks(16B)
        int co = i & 15; int pos = i >> 4; int xx = pos % 20; int yy = pos / 20;
        int gy = y0 + yy - 2, gx = x0 + xx - 2;
        uint4 v = make_uint4(0, 0, 0, 0);
        if (gy >= 0 && gy < 96 && gx >= 0 && gx < 96)
            v = *(const uint4*)&xph[((((b * 96 + gy) * 96 + gx)) << 7) + (co << 3)];
        *(uint4*)&xl[(yy * 20 + xx) * 136 + (co << 3)] = v;
    }
    __syncthreads();

    f32x4 acc0 = {}, acc1 = {};
    const f16x8* A = (const f16x8*)wfA;
    f16x8 bbC[4], a0C[4], a1C[4];
    {
        int rowb = (wv * 20 + n) * 136 + quad * 8;
#pragma unroll
        for (int cib = 0; cib < 4; cib++) {
            bbC[cib] = *(const f16x8*)&xl[rowb + cib * 32];
            a0C[cib] = A[cib * 64 + lane];
            a1C[cib] = A[(100 + cib) * 64 + lane];
        }
    }
#pragma unroll 1
    for (int tap = 0; tap < 25; tap++) {
        f16x8 bbN[4], a0N[4], a1N[4];
        if (tap < 24) {
            int tn = tap + 1;
            int dy = tn / 5, dx = tn % 5;
            int rowb = ((wv + dy) * 20 + n + dx) * 136 + quad * 8;
#pragma unroll
            for (int cib = 0; cib < 4; cib++) {
                bbN[cib] = *(const f16x8*)&xl[rowb + cib * 32];
                a0N[cib] = A[(tn * 4 + cib) * 64 + lane];
                a1N[cib] = A[((25 + tn) * 4 + cib) * 64 + lane];
            }
        }
#pragma unroll
        for (int cib = 0; cib < 4; cib++) {
            acc0 = __builtin_amdgcn_mfma_f32_16x16x32_f16(a0C[cib], bbC[cib], acc0, 0, 0, 0);
            acc1 = __builtin_amdgcn_mfma_f32_16x16x32_f16(a1C[cib], bbC[cib], acc1, 0, 0, 0);
        }
#pragma unroll
        for (int cib = 0; cib < 4; cib++) {
            bbC[cib] = bbN[cib]; a0C[cib] = a0N[cib]; a1C[cib] = a1N[cib];
        }
    }

    int base = (((b * 96 + y0 + wv) * 96 + x0 + n)) * 32 + quad * 4;
    {
        u16 p[4];
#pragma unroll
        for (int r2 = 0; r2 < 4; r2++) {
            int oc = quad * 4 + r2;
            float v = acc0[r2] + biases[192 + oc] + biases[224 + oc];
            v = (v > 0.f) ? v : NEG * v;
            p[r2] = f2h(v);
        }
        *(uint2*)&fT[base] = make_uint2(p[0] | ((u32)p[1] << 16), p[2] | ((u32)p[3] << 16));
#pragma unroll
        for (int r2 = 0; r2 < 4; r2++) {
            int oc = 16 + quad * 4 + r2;
            float v = acc1[r2] + biases[192 + oc] + biases[224 + oc];
            v = (v > 0.f) ? v : NEG * v;
            p[r2] = f2h(v);
        }
        *(uint2*)&fT[base + 16] = make_uint2(p[0] | ((u32)p[1] << 16), p[2] | ((u32)p[3] << 16));
    }
}

// ---------------- K3: flows 5x5 conv (32 -> 26) via MFMA, out NCHW f32 -------
__global__ __launch_bounds__(256) void k_flows(const u16* __restrict__ fT,
        const u16* __restrict__ wlA, const float* __restrict__ biases,
        float* __restrict__ flows)
{
    __shared__ __align__(16) u16 xl[8 * 20 * 40];   // 12800 B, x-stride 40
    int lin = blockIdx.x;            // 0..1151
    int b = lin & 7;
    int r = lin >> 3;                // 0..143
    int x0 = (r % 6) * 16, y0 = (r / 6) * 4;
    int t = threadIdx.x, lane = t & 63, wv = t >> 6;
    int n = lane & 15, quad = lane >> 4;

    for (int i = t; i < 640; i += 256) {    // 160 pos x 4 chunks(16B)
        int co = i & 3; int pos = i >> 2; int xx = pos % 20; int yy = pos / 20;
        int gy = y0 + yy - 2, gx = x0 + xx - 2;
        uint4 v = make_uint4(0, 0, 0, 0);
        if (gy >= 0 && gy < 96 && gx >= 0 && gx < 96)
            v = *(const uint4*)&fT[((((b * 96 + gy) * 96 + gx)) << 5) + (co << 3)];
        *(uint4*)&xl[(yy * 20 + xx) * 40 + (co << 3)] = v;
    }
    __syncthreads();

    f32x4 acc0 = {}, acc1 = {};
    const f16x8* A = (const f16x8*)wlA;
#pragma unroll 5
    for (int tap = 0; tap < 25; tap++) {
        int dy = tap / 5, dx = tap % 5;
        f16x8 bb = *(const f16x8*)&xl[((wv + dy) * 20 + n + dx) * 40 + quad * 8];
        f16x8 a0 = A[tap * 64 + lane];
        f16x8 a1 = A[(25 + tap) * 64 + lane];
        acc0 = __builtin_amdgcn_mfma_f32_16x16x32_f16(a0, bb, acc0, 0, 0, 0);
        acc1 = __builtin_amdgcn_mfma_f32_16x16x32_f16(a1, bb, acc1, 0, 0, 0);
    }

    int pix = (y0 + wv) * 96 + x0 + n;
#pragma unroll
    for (int r2 = 0; r2 < 4; r2++) {
        int oc = quad * 4 + r2;
        flows[(b * 26 + oc) * 9216 + pix] = acc0[r2] + biases[256 + oc];
        int oc1 = 16 + quad * 4 + r2;
        if (oc1 < 26)
            flows[(b * 26 + oc1) * 9216 + pix] = acc1[r2] + biases[256 + oc1];
    }
}

// ---------------- K4: i2h conv + warp + 1x1 conv + gates (fully fused) ------
// R9: the 18 i2h (tap,cib) iterations are INTERLEAVED into the 13-link
// gather/GEMM loop (1-2 per link, static schedule floor(18l/13)). The i2h
// MFMAs fill the bilinear-gather latency window; the GEMM gives i2h A-loads
// ~3x more cover. Accumulation order per accumulator unchanged -> bitwise
// identical to R8. Wave wv owns mt={wv,wv+4,wv+8} -> gates fully in regs.
__global__ __launch_bounds__(256, 4) void k_fused(const float* __restrict__ flows,
        const u16* __restrict__ xph, const u16* __restrict__ wiA,
        const u16* __restrict__ wretA, const float* __restrict__ biases,
        void* __restrict__ out, const u32* __restrict__ flag)
{
    __shared__ __align__(16) char sm[26368];
    u16* xi  = (u16*)sm;                                  // [3][34][64] swz, 13056 B
    u16* pvs = (u16*)(sm + 13056);                        // [32][64] swz, 4096 B
    u16 (*gb)[32][72] = (u16 (*)[32][72])(sm + 17152);    // [2][32][72], 9216 B
    float* wst = (float*)(sm + 17152);                    // [64][32] f32 overlay

    int flg = (int)flag[0];
    int lin = blockIdx.x;            // 0..2303
    int b = lin & 7;
    int r = lin >> 3;                // 0..287
    int w0 = (r % 3) * 32;
    int h = r / 3;
    int t = threadIdx.x;
    int lane = t & 63, wv = t >> 6;
    const float S = 96.f / 95.f;
    int hrow = h * 96 + w0;

    // ---- stage xi (3-row x-channel halo, px=gx-w0+1 in [0,34)) + pvs ----
#pragma unroll 1
    for (int i = t; i < 816; i += 256) {    // 102 pos x 8 chunks
        int co = i & 7; int pos = i >> 3;
        int px = pos % 34, dy = pos / 34;
        int gy = h + dy - 1, gx = w0 + px - 1;
        uint4 v = make_uint4(0, 0, 0, 0);
        if (gy >= 0 && gy < 96 && gx >= 0 && gx < 96)
            v = *(const uint4*)&xph[(((b * 96 + gy) * 96 + gx) << 7) + (co << 3)];
        *(uint4*)&xi[((dy * 34 + px) << 6) + ((co ^ (px & 7)) << 3)] = v;
    }
    {   // pvs: 32 px x 8 chunks of ph-channels at own row (1 chunk/thread)
        int co = t & 7; int px = t >> 3;
        uint4 v = *(const uint4*)&xph[(((b * 96 + h) * 96 + w0 + px) << 7) + 64 + (co << 3)];
        *(uint4*)&pvs[(px << 6) + ((co ^ (px & 7)) << 3)] = v;
    }
    __syncthreads();

    int p = t >> 3, sub = t & 7;
    const float* fl = &flows[b * 26 * 9216 + hrow + p];
    const u16* xb = &xph[(b * 96) * 96 * 128 + 64 + sub * 8];

    int n = lane & 15, q = lane >> 4;
    const f16x8* Ap = (const f16x8*)wretA;
    const f16x8* Ai = (const f16x8*)wiA;
    const f16x8 zv = {};

    f32x4 acc2[3][2] = {};   // i2h accumulators
    f32x4 acc[3][2] = {};    // h2h accumulators
    f16x8 c00, c10, c01, c11; float cwx, cwy;
    f16x8 n00, n10, n01, n11; float nwx, nwy;

#define GISSUE(DX, DY, V00, V10, V01, V11, WX, WY)                         \
    {                                                                      \
        float px_ = ((float)(w0 + p) - (DX)) * S - 0.5f;                   \
        float py_ = ((float)h - (DY)) * S - 0.5f;                          \
        float fx = floorf(px_), fy = floorf(py_);                          \
        int ix = (int)fx, iy = (int)fy;                                    \
        WX = px_ - fx; WY = py_ - fy;                                      \
        bool xv0 = (ix >= 0) & (ix < 96);                                  \
        bool xv1 = (ix >= -1) & (ix < 95);                                 \
        bool yv0 = (iy >= 0) & (iy < 96);                                  \
        bool yv1 = (iy >= -1) & (iy < 95);                                 \
        V00 = zv; V10 = zv; V01 = zv; V11 = zv;                            \
        if (yv0) {                                                         \
            const u16* rr = xb + (iy * 96 + ix) * 128;                     \
            if (xv0) V00 = *(const f16x8*)rr;                              \
            if (xv1) V10 = *(const f16x8*)(rr + 128);                      \
        }                                                                  \
        if (yv1) {                                                         \
            const u16* rr = xb + ((iy + 1) * 96 + ix) * 128;               \
            if (xv0) V01 = *(const f16x8*)rr;                              \
            if (xv1) V11 = *(const f16x8*)(rr + 128);                      \
        }                                                                  \
    }

    // prologue: flow scalars for links 0,1; gather issue for link 0;
    // first i2h A-frags
    float fdxc = fl[0 * 9216], fdyc = fl[1 * 9216];
    float fdxn = fl[2 * 9216], fdyn = fl[3 * 9216];
    GISSUE(fdxc, fdyc, c00, c10, c01, c11, cwx, cwy);
    f16x8 aC[3], aN[3];
#pragma unroll
    for (int mi = 0; mi < 3; mi++)
        aC[mi] = Ai[(((wv + 4 * mi) * 9 + 0) * 2 + 0) * 64 + lane];

#pragma unroll
    for (int l = 0; l < 13; l++) {
        float fdx2 = 0.f, fdy2 = 0.f;
        if (l + 2 < 13) { fdx2 = fl[(2 * l + 4) * 9216]; fdy2 = fl[(2 * l + 5) * 9216]; }
        if (l + 1 < 13) GISSUE(fdxn, fdyn, n00, n10, n01, n11, nwx, nwy);

        // i2h slice for this link: it in [18l/13, 18(l+1)/13) — 1 or 2 iters
#pragma unroll
        for (int it = (18 * l) / 13; it < (18 * (l + 1)) / 13; it++) {
            if (it + 1 < 18) {
                int tn = it + 1; int tapn = tn >> 1, cibn = tn & 1;
#pragma unroll
                for (int mi = 0; mi < 3; mi++)
                    aN[mi] = Ai[(((wv + 4 * mi) * 9 + tapn) * 2 + cibn) * 64 + lane];
            }
            int tap = it >> 1, cib = it & 1;
            int dy = tap / 3, dx = tap % 3;
            __builtin_amdgcn_s_setprio(1);
#pragma unroll
            for (int g = 0; g < 2; g++) {
                int px = g * 16 + n + dx;
                int cor = (cib * 4 + q) ^ (px & 7);
                f16x8 bb = *(const f16x8*)&xi[((dy * 34 + px) << 6) + (cor << 3)];
#pragma unroll
                for (int mi = 0; mi < 3; mi++)
                    acc2[mi][g] = __builtin_amdgcn_mfma_f32_16x16x32_f16(aC[mi], bb, acc2[mi][g], 0, 0, 0);
            }
            __builtin_amdgcn_s_setprio(0);
#pragma unroll
            for (int mi = 0; mi < 3; mi++) aC[mi] = aN[mi];
        }

        // interp current link's gather -> gb
        {
            float w00 = (1.f - cwx) * (1.f - cwy), w10 = cwx * (1.f - cwy);
            float w01 = (1.f - cwx) * cwy,         w11 = cwx * cwy;
            u16 res[8];
#pragma unroll
            for (int j = 0; j < 8; j++) {
                float v = w00 * (float)c00[j] + w10 * (float)c10[j]
                        + w01 * (float)c01[j] + w11 * (float)c11[j];
                res[j] = f2h(v);
            }
            uint4 o;
            o.x = res[0] | ((u32)res[1] << 16); o.y = res[2] | ((u32)res[3] << 16);
            o.z = res[4] | ((u32)res[5] << 16); o.w = res[6] | ((u32)res[7] << 16);
            *(uint4*)&gb[l & 1][p][sub * 8] = o;
        }
        __syncthreads();
        __builtin_amdgcn_s_setprio(1);
#pragma unroll
        for (int ksl = 0; ksl < 2; ksl++) {
            int ks = 2 * l + ksl;
            f16x8 b0 = *(const f16x8*)&gb[l & 1][n][ksl * 32 + q * 8];
            f16x8 b1 = *(const f16x8*)&gb[l & 1][16 + n][ksl * 32 + q * 8];
#pragma unroll
            for (int mi = 0; mi < 3; mi++) {
                f16x8 a = Ap[((wv + 4 * mi) * 26 + ks) * 64 + lane];
                acc[mi][0] = __builtin_amdgcn_mfma_f32_16x16x32_f16(a, b0, acc[mi][0], 0, 0, 0);
                acc[mi][1] = __builtin_amdgcn_mfma_f32_16x16x32_f16(a, b1, acc[mi][1], 0, 0, 0);
            }
        }
        __builtin_amdgcn_s_setprio(0);
        c00 = n00; c10 = n10; c01 = n01; c11 = n11; cwx = nwx; cwy = nwy;
        fdxc = fdxn; fdyc = fdyn; fdxn = fdx2; fdyn = fdy2;
    }
#undef GISSUE

    __syncthreads();   // gb dead; wst may overwrite it

    // ---- gates fully in registers; stage nh -> wst ----
#pragma unroll
    for (int ni = 0; ni < 2; ni++)
#pragma unroll
        for (int r2 = 0; r2 < 4; r2++) {
            int ocg = wv * 16 + q * 4 + r2;      // 0..63
            int px = ni * 16 + n;
            float i0 = acc2[0][ni][r2] + biases[ocg];
            float i1 = acc2[1][ni][r2] + biases[64 + ocg];
            float i2 = acc2[2][ni][r2] + biases[128 + ocg];
            float h0 = acc[0][ni][r2] + biases[282 + ocg];
            float h1 = acc[1][ni][r2] + biases[282 + 64 + ocg];
            float h2 = acc[2][ni][r2] + biases[282 + 128 + ocg];
            int cor = (ocg >> 3) ^ (px & 7);
            float pv = h2f(pvs[(px << 6) + (cor << 3) + (ocg & 7)]);
            float rg = sigm(i0 + h0);
            float ug = sigm(i1 + h1);
            float nm = i2 + rg * h2;
            nm = (nm > 0.f) ? nm : NEG * nm;
            wst[ocg * 32 + px] = ug * pv + (1.f - ug) * nm;
        }
    __syncthreads();

    // ---- write-out: coalesced stores of both copies ----
#pragma unroll 1
    for (int j = 0; j < 8; j++) {
        int i = t + 256 * j;
        int pp = i & 31, cc = i >> 5;
        float nh = wst[cc * 32 + pp];
        int oidx = ((b * 64 + cc) * 96 + h) * 96 + w0 + pp;
        if (flg) {
            float* of = (float*)out;
            of[oidx] = nh;
            of[oidx + 2 * 4718592] = nh;
        } else {
            u16* ob16 = (u16*)out;
            u16 v = f2b(nh);
            ob16[oidx] = v;
            ob16[oidx + 2 * 4718592] = v;
        }
    }
}

// ---------------- K5: copy m passthrough (dtype-size aware) ----------------
__global__ void kcopym(const uint4* __restrict__ m, uint4* __restrict__ out,
                       const u32* __restrict__ flag)
{
    int flg = (int)flag[0];
    int n4 = flg ? 1179648 : 589824;   // uint4 chunks per tensor
    int stride = gridDim.x * 256;
    for (int i = blockIdx.x * 256 + threadIdx.x; i < n4; i += stride)
        out[n4 + i] = m[i];
}

extern "C" void kernel_launch(void* const* d_in, const int* in_sizes, int n_in,
                              void* d_out, int out_size, void* d_ws, size_t ws_size,
                              hipStream_t stream)
{
    const void* x     = d_in[0];
    const void* m     = d_in[1];
    const void* ph    = d_in[2];
    const void* w_i2h = d_in[3];
    const void* b_i2h = d_in[4];
    const void* w_i2f = d_in[5];
    const void* b_i2f = d_in[6];
    const void* w_h2f = d_in[7];
    const void* b_h2f = d_in[8];
    const void* w_fl  = d_in[9];
    const void* b_fl  = d_in[10];
    const void* w_ret = d_in[11];
    const void* b_ret = d_in[12];

    char* ws = (char*)d_ws;
    u32*    flag   = (u32*)  (ws + 0);
    u16*    wiA    = (u16*)  (ws + 64);
    u16*    wfA    = (u16*)  (ws + 221248);
    u16*    wlA    = (u16*)  (ws + 426048);
    u16*    wretA  = (u16*)  (ws + 477248);
    float*  biases = (float*)(ws + 796736);
    u16*    xph    = (u16*)  (ws + 798784);
    u16*    fT     = (u16*)  (ws + 47984704);
    float*  flows  = (float*)(ws + 52703296);
    if (ws_size < WS_NEED) return;  // diagnostic signature: absmax == max|ref|

    kdetect<<<1, 256, 0, stream>>>((const u16*)x, flag);
    kprep<<<624, 256, 0, stream>>>(w_i2h, w_i2f, w_h2f, w_fl, w_ret,
                                   b_i2h, b_i2f, b_h2f, b_fl, b_ret,
                                   wiA, wfA, wlA, wretA, biases, flag);
    kxph<<<dim3(96, 8), 256, 0, stream>>>(x, ph, xph, flag);
    k_flowfeat<<<dim3(1152), 256, 0, stream>>>(xph, wfA, biases, fT);
    k_flows<<<dim3(1152), 256, 0, stream>>>(fT, wlA, biases, flows);
    k_fused<<<dim3(2304), 256, 0, stream>>>(flows, xph, wiA, wretA, biases,
                                            d_out, flag);
    kcopym<<<2048, 256, 0, stream>>>((const uint4*)m, (uint4*)d_out, flag);
}

// Round 10
// 279.959 us; speedup vs baseline: 1.3811x; 1.3811x over previous
//
#include <hip/hip_runtime.h>
#include <hip/hip_bf16.h>
#include <hip/hip_fp16.h>

typedef unsigned short u16;
typedef unsigned int u32;
typedef __attribute__((ext_vector_type(8))) _Float16 f16x8;
typedef __attribute__((ext_vector_type(4))) float f32x4;

#define NEG 0.2f

__device__ __forceinline__ float bf2f(u16 u) {
    return __uint_as_float(((u32)u) << 16);
}
__device__ __forceinline__ u16 f2b(float f) {   // round-to-nearest-even f32->bf16
    u32 u = __float_as_uint(f);
    u32 r = (u + 0x7FFF + ((u >> 16) & 1)) >> 16;
    return (u16)r;
}
__device__ __forceinline__ u16 f2h(float f) {   // f32 -> f16 bits
    return __half_as_ushort(__float2half(f));
}
__device__ __forceinline__ float h2f(u16 u) {
    return __half2float(__ushort_as_half(u));
}
__device__ __forceinline__ float sigm(float x) {
    return 1.0f / (1.0f + __expf(-x));
}
__device__ __forceinline__ float ldin(const void* p, int idx, int flag) {
    if (flag) return ((const float*)p)[idx];
    return bf2f(((const u16*)p)[idx]);
}
__device__ __forceinline__ u16 ldin_h(const void* p, int idx, int flag) {  // -> f16 bits
    if (flag) return f2h(((const float*)p)[idx]);
    return f2h(bf2f(((const u16*)p)[idx]));
}

// ---------------- ws layout (bytes) ----------------
// flag    u32                        @ 0          (64)
// wiA     f16 [12][9][2][64][8]      @ 64         (221184)  i2h A-frags
// wfA     f16 [2][25][4][64][8]      @ 221248     (204800)  flowfeat A-frags
// wlA     f16 [2][25][64][8]         @ 426048     (51200)   flows A-frags
// wretA   f16 [12][26][64][8]        @ 477248     (319488)  ret A-frags
// biases  f32 [474]                  @ 796736     (2048)
// xph     f16 [8][96][96][128]       @ 798784     (18874368)  NHWC x||prev_h
// (i2hT region unused since R8 fusion)
// fT      f16 [8][96][96][32]        @ 47984704   (4718592)
// flows   f32 [8][26][96][96]        @ 52703296   (7667712)
// total: 60371008

#define WS_NEED 60371008u

// ---------------- K-1: dtype detect ----------------
__global__ void kdetect(const u16* __restrict__ x, u32* __restrict__ flag)
{
    __shared__ u32 mx[256];
    int t = threadIdx.x;
    u32 m = 0;
    for (int i = t; i < 8192; i += 256) {
        u32 e = ((u32)x[i] >> 7) & 0xFF;
        m = m > e ? m : e;
    }
    mx[t] = m;
    __syncthreads();
    for (int s = 128; s > 0; s >>= 1) {
        if (t < s) mx[t] = mx[t] > mx[t + s] ? mx[t] : mx[t + s];
        __syncthreads();
    }
    if (t == 0) flag[0] = (mx[0] > 0xC0) ? 1u : 0u;
}

// ---------------- K0a: weight repack -> MFMA A-fragments (f16) ----------------
__global__ void kprep(const void* __restrict__ w_i2h, const void* __restrict__ w_i2f,
                      const void* __restrict__ w_h2f, const void* __restrict__ w_fl,
                      const void* __restrict__ w_ret,
                      const void* __restrict__ b_i2h, const void* __restrict__ b_i2f,
                      const void* __restrict__ b_h2f, const void* __restrict__ b_fl,
                      const void* __restrict__ b_ret,
                      u16* __restrict__ wiA, u16* __restrict__ wfA,
                      u16* __restrict__ wlA, u16* __restrict__ wretA,
                      float* __restrict__ biases, const u32* __restrict__ flag)
{
    int flg = (int)flag[0];
    int i = blockIdx.x * 256 + threadIdx.x;
    // A-frag pattern: A[m=lane&15][k=(lane>>4)*8+j]  (validated R4)
    if (i < 110592) {                 // wiA [mt12][tap9][cib2][lane][j]
        int j = i & 7; int lane = (i >> 3) & 63; int rest = i >> 9;
        int cib = rest & 1; int rest2 = rest >> 1;
        int tap = rest2 % 9; int mt = rest2 / 9;
        int oc = mt * 16 + (lane & 15);
        int ci = cib * 32 + ((lane >> 4) << 3) + j;
        wiA[i] = ldin_h(w_i2h, (oc * 64 + ci) * 9 + tap, flg);
    }
    if (i < 102400) {                 // wfA [mt2][tap25][cib4][lane][j]
        int j = i & 7; int lane = (i >> 3) & 63; int rest = i >> 9;
        int cib = rest & 3; int rest2 = rest >> 2;
        int tap = rest2 % 25; int mt = rest2 / 25;
        int oc = mt * 16 + (lane & 15);
        int cip = cib * 32 + ((lane >> 4) << 3) + j;
        wfA[i] = (cip < 64) ? ldin_h(w_i2f, (oc * 64 + cip) * 25 + tap, flg)
                            : ldin_h(w_h2f, (oc * 64 + cip - 64) * 25 + tap, flg);
    }
    if (i < 25600) {                  // wlA [mt2][tap25][lane][j], oc>=26 -> 0
        int j = i & 7; int lane = (i >> 3) & 63; int rest = i >> 9;
        int tap = rest % 25; int mt = rest / 25;
        int oc = mt * 16 + (lane & 15);
        int ci = ((lane >> 4) << 3) + j;
        wlA[i] = (oc < 26) ? ldin_h(w_fl, (oc * 32 + ci) * 25 + tap, flg) : (u16)0;
    }
    if (i < 159744) {                 // wretA [mt12][ks26][lane][j]
        int j = i & 7; int l = (i >> 3) & 63; int rest = i >> 9;
        int ks = rest % 26; int mt = rest / 26;
        int o = mt * 16 + (l & 15);
        int k = ks * 32 + ((l >> 4) << 3) + j;
        wretA[i] = ldin_h(w_ret, o * 832 + k, flg);
    }
    if (i < 474) {
        float v;
        if (i < 192)      v = ldin(b_i2h, i, flg);
        else if (i < 224) v = ldin(b_i2f, i - 192, flg);
        else if (i < 256) v = ldin(b_h2f, i - 224, flg);
        else if (i < 282) v = ldin(b_fl, i - 256, flg);
        else              v = ldin(b_ret, i - 282, flg);
        biases[i] = v;
    }
}

// ---------------- K0b: x, prev_h (NCHW) -> xph NHWC f16 [B][H][W][128] ------
__global__ __launch_bounds__(256) void kxph(const void* __restrict__ x,
        const void* __restrict__ ph, u16* __restrict__ xph,
        const u32* __restrict__ flag)
{
    __shared__ __align__(16) u16 tile[64 * 104];
    int flg = (int)flag[0];
    int h = blockIdx.x, b = blockIdx.y;
    int t = threadIdx.x;
#pragma unroll 1
    for (int s = 0; s < 2; s++) {
        const void* src = s ? ph : x;
#pragma unroll 1
        for (int i = t; i < 768; i += 256) {      // 64 c x 12 w-chunks of 8
            int wc = i % 12, c = i / 12;
            int base = ((b * 64 + c) * 96 + h) * 96 + wc * 8;
            u16 r[8];
            if (flg) {
                const float* sp = (const float*)src + base;
                float4 f0 = *(const float4*)sp;
                float4 f1 = *(const float4*)(sp + 4);
                r[0] = f2h(f0.x); r[1] = f2h(f0.y); r[2] = f2h(f0.z); r[3] = f2h(f0.w);
                r[4] = f2h(f1.x); r[5] = f2h(f1.y); r[6] = f2h(f1.z); r[7] = f2h(f1.w);
            } else {
                const u16* sp = (const u16*)src + base;
                uint4 u = *(const uint4*)sp;
                r[0] = f2h(bf2f((u16)(u.x & 0xFFFF))); r[1] = f2h(bf2f((u16)(u.x >> 16)));
                r[2] = f2h(bf2f((u16)(u.y & 0xFFFF))); r[3] = f2h(bf2f((u16)(u.y >> 16)));
                r[4] = f2h(bf2f((u16)(u.z & 0xFFFF))); r[5] = f2h(bf2f((u16)(u.z >> 16)));
                r[6] = f2h(bf2f((u16)(u.w & 0xFFFF))); r[7] = f2h(bf2f((u16)(u.w >> 16)));
            }
            uint4 o;
            o.x = r[0] | ((u32)r[1] << 16); o.y = r[2] | ((u32)r[3] << 16);
            o.z = r[4] | ((u32)r[5] << 16); o.w = r[6] | ((u32)r[7] << 16);
            *(uint4*)&tile[c * 104 + wc * 8] = o;
        }
        __syncthreads();
#pragma unroll 1
        for (int i = t; i < 768; i += 256) {      // 96 w x 8 c-groups of 8
            int cg = i & 7, w = i >> 3;
            u16 v[8];
#pragma unroll
            for (int k = 0; k < 8; k++) v[k] = tile[(cg * 8 + k) * 104 + w];
            uint4 o;
            o.x = v[0] | ((u32)v[1] << 16); o.y = v[2] | ((u32)v[3] << 16);
            o.z = v[4] | ((u32)v[5] << 16); o.w = v[6] | ((u32)v[7] << 16);
            *(uint4*)&xph[(((b * 96 + h) * 96 + w) << 7) + s * 64 + cg * 8] = o;
        }
        __syncthreads();
    }
}

// ---------------- K2: flowfeat 5x5 conv (128 -> 32) via MFMA, out NHWC f16 --
__global__ __launch_bounds__(256) void k_flowfeat(const u16* __restrict__ xph,
        const u16* __restrict__ wfA, const float* __restrict__ biases,
        u16* __restrict__ fT)
{
    __shared__ __align__(16) u16 xl[8 * 20 * 136];   // 43520 B, x-stride 136
    int lin = blockIdx.x;            // 0..1151
    int b = lin & 7;
    int r = lin >> 3;                // 0..143
    int x0 = (r % 6) * 16, y0 = (r / 6) * 4;
    int t = threadIdx.x, lane = t & 63, wv = t >> 6;
    int n = lane & 15, quad = lane >> 4;

    for (int i = t; i < 2560; i += 256) {   // 160 pos x 16 chunks(16B)
        int co = i & 15; int pos = i >> 4; int xx = pos % 20; int yy = pos / 20;
        int gy = y0 + yy - 2, gx = x0 + xx - 2;
        uint4 v = make_uint4(0, 0, 0, 0);
        if (gy >= 0 && gy < 96 && gx >= 0 && gx < 96)
            v = *(const uint4*)&xph[((((b * 96 + gy) * 96 + gx)) << 7) + (co << 3)];
        *(uint4*)&xl[(yy * 20 + xx) * 136 + (co << 3)] = v;
    }
    __syncthreads();

    f32x4 acc0 = {}, acc1 = {};
    const f16x8* A = (const f16x8*)wfA;
    f16x8 bbC[4], a0C[4], a1C[4];
    {
        int rowb = (wv * 20 + n) * 136 + quad * 8;
#pragma unroll
        for (int cib = 0; cib < 4; cib++) {
            bbC[cib] = *(const f16x8*)&xl[rowb + cib * 32];
            a0C[cib] = A[cib * 64 + lane];
            a1C[cib] = A[(100 + cib) * 64 + lane];
        }
    }
#pragma unroll 1
    for (int tap = 0; tap < 25; tap++) {
        f16x8 bbN[4], a0N[4], a1N[4];
        if (tap < 24) {
            int tn = tap + 1;
            int dy = tn / 5, dx = tn % 5;
            int rowb = ((wv + dy) * 20 + n + dx) * 136 + quad * 8;
#pragma unroll
            for (int cib = 0; cib < 4; cib++) {
                bbN[cib] = *(const f16x8*)&xl[rowb + cib * 32];
                a0N[cib] = A[(tn * 4 + cib) * 64 + lane];
                a1N[cib] = A[((25 + tn) * 4 + cib) * 64 + lane];
            }
        }
#pragma unroll
        for (int cib = 0; cib < 4; cib++) {
            acc0 = __builtin_amdgcn_mfma_f32_16x16x32_f16(a0C[cib], bbC[cib], acc0, 0, 0, 0);
            acc1 = __builtin_amdgcn_mfma_f32_16x16x32_f16(a1C[cib], bbC[cib], acc1, 0, 0, 0);
        }
#pragma unroll
        for (int cib = 0; cib < 4; cib++) {
            bbC[cib] = bbN[cib]; a0C[cib] = a0N[cib]; a1C[cib] = a1N[cib];
        }
    }

    int base = (((b * 96 + y0 + wv) * 96 + x0 + n)) * 32 + quad * 4;
    {
        u16 p[4];
#pragma unroll
        for (int r2 = 0; r2 < 4; r2++) {
            int oc = quad * 4 + r2;
            float v = acc0[r2] + biases[192 + oc] + biases[224 + oc];
            v = (v > 0.f) ? v : NEG * v;
            p[r2] = f2h(v);
        }
        *(uint2*)&fT[base] = make_uint2(p[0] | ((u32)p[1] << 16), p[2] | ((u32)p[3] << 16));
#pragma unroll
        for (int r2 = 0; r2 < 4; r2++) {
            int oc = 16 + quad * 4 + r2;
            float v = acc1[r2] + biases[192 + oc] + biases[224 + oc];
            v = (v > 0.f) ? v : NEG * v;
            p[r2] = f2h(v);
        }
        *(uint2*)&fT[base + 16] = make_uint2(p[0] | ((u32)p[1] << 16), p[2] | ((u32)p[3] << 16));
    }
}

// ---------------- K3: flows 5x5 conv (32 -> 26) via MFMA, out NCHW f32 -------
__global__ __launch_bounds__(256) void k_flows(const u16* __restrict__ fT,
        const u16* __restrict__ wlA, const float* __restrict__ biases,
        float* __restrict__ flows)
{
    __shared__ __align__(16) u16 xl[8 * 20 * 40];   // 12800 B, x-stride 40
    int lin = blockIdx.x;            // 0..1151
    int b = lin & 7;
    int r = lin >> 3;                // 0..143
    int x0 = (r % 6) * 16, y0 = (r / 6) * 4;
    int t = threadIdx.x, lane = t & 63, wv = t >> 6;
    int n = lane & 15, quad = lane >> 4;

    for (int i = t; i < 640; i += 256) {    // 160 pos x 4 chunks(16B)
        int co = i & 3; int pos = i >> 2; int xx = pos % 20; int yy = pos / 20;
        int gy = y0 + yy - 2, gx = x0 + xx - 2;
        uint4 v = make_uint4(0, 0, 0, 0);
        if (gy >= 0 && gy < 96 && gx >= 0 && gx < 96)
            v = *(const uint4*)&fT[((((b * 96 + gy) * 96 + gx)) << 5) + (co << 3)];
        *(uint4*)&xl[(yy * 20 + xx) * 40 + (co << 3)] = v;
    }
    __syncthreads();

    f32x4 acc0 = {}, acc1 = {};
    const f16x8* A = (const f16x8*)wlA;
#pragma unroll 5
    for (int tap = 0; tap < 25; tap++) {
        int dy = tap / 5, dx = tap % 5;
        f16x8 bb = *(const f16x8*)&xl[((wv + dy) * 20 + n + dx) * 40 + quad * 8];
        f16x8 a0 = A[tap * 64 + lane];
        f16x8 a1 = A[(25 + tap) * 64 + lane];
        acc0 = __builtin_amdgcn_mfma_f32_16x16x32_f16(a0, bb, acc0, 0, 0, 0);
        acc1 = __builtin_amdgcn_mfma_f32_16x16x32_f16(a1, bb, acc1, 0, 0, 0);
    }

    int pix = (y0 + wv) * 96 + x0 + n;
#pragma unroll
    for (int r2 = 0; r2 < 4; r2++) {
        int oc = quad * 4 + r2;
        flows[(b * 26 + oc) * 9216 + pix] = acc0[r2] + biases[256 + oc];
        int oc1 = 16 + quad * 4 + r2;
        if (oc1 < 26)
            flows[(b * 26 + oc1) * 9216 + pix] = acc1[r2] + biases[256 + oc1];
    }
}

// ---------------- K4: i2h conv + warp + 1x1 conv + gates (fully fused) ------
// R10 = R8 structure (best verified) + one reorder: link-0 bilinear gather
// issued BEFORE the i2h phase, so its ~700-cyc load chain hides under the 36
// i2h MFMAs. R9's full interleave spilled (aC/aN live through link loop);
// here only the 4 gather f16x8s (+18 VGPR) span phase 1 — no spill at the
// (256,4) budget. Math/accumulation order identical to R8.
__global__ __launch_bounds__(256, 4) void k_fused(const float* __restrict__ flows,
        const u16* __restrict__ xph, const u16* __restrict__ wiA,
        const u16* __restrict__ wretA, const float* __restrict__ biases,
        void* __restrict__ out, const u32* __restrict__ flag)
{
    __shared__ __align__(16) char sm[26368];
    u16* xi  = (u16*)sm;                                  // [3][34][64] swz, 13056 B
    u16* pvs = (u16*)(sm + 13056);                        // [32][64] swz, 4096 B
    u16 (*gb)[32][72] = (u16 (*)[32][72])(sm + 17152);    // [2][32][72], 9216 B
    float* wst = (float*)(sm + 17152);                    // [64][32] f32 overlay

    int flg = (int)flag[0];
    int lin = blockIdx.x;            // 0..2303
    int b = lin & 7;
    int r = lin >> 3;                // 0..287
    int w0 = (r % 3) * 32;
    int h = r / 3;
    int t = threadIdx.x;
    int lane = t & 63, wv = t >> 6;
    const float S = 96.f / 95.f;
    int hrow = h * 96 + w0;

    // ---- stage xi (3-row x-channel halo, px=gx-w0+1 in [0,34)) + pvs ----
#pragma unroll 1
    for (int i = t; i < 816; i += 256) {    // 102 pos x 8 chunks
        int co = i & 7; int pos = i >> 3;
        int px = pos % 34, dy = pos / 34;
        int gy = h + dy - 1, gx = w0 + px - 1;
        uint4 v = make_uint4(0, 0, 0, 0);
        if (gy >= 0 && gy < 96 && gx >= 0 && gx < 96)
            v = *(const uint4*)&xph[(((b * 96 + gy) * 96 + gx) << 7) + (co << 3)];
        *(uint4*)&xi[((dy * 34 + px) << 6) + ((co ^ (px & 7)) << 3)] = v;
    }
    {   // pvs: 32 px x 8 chunks of ph-channels at own row (1 chunk/thread)
        int co = t & 7; int px = t >> 3;
        uint4 v = *(const uint4*)&xph[(((b * 96 + h) * 96 + w0 + px) << 7) + 64 + (co << 3)];
        *(uint4*)&pvs[(px << 6) + ((co ^ (px & 7)) << 3)] = v;
    }

    int p = t >> 3, sub = t & 7;
    const float* fl = &flows[b * 26 * 9216 + hrow + p];
    const u16* xb = &xph[(b * 96) * 96 * 128 + 64 + sub * 8];

    int n = lane & 15, q = lane >> 4;
    const f16x8* Ap = (const f16x8*)wretA;
    const f16x8* Ai = (const f16x8*)wiA;
    const f16x8 zv = {};

    // flow loads for links 0,1 + link-0 gather issued BEFORE the i2h phase:
    // their latency hides under the 36 i2h MFMAs (R10 reorder).
    float fdxc = fl[0 * 9216], fdyc = fl[1 * 9216];
    float fdxn = fl[2 * 9216], fdyn = fl[3 * 9216];

    f16x8 c00, c10, c01, c11; float cwx, cwy;
    f16x8 n00, n10, n01, n11; float nwx, nwy;

#define GISSUE(DX, DY, V00, V10, V01, V11, WX, WY)                         \
    {                                                                      \
        float px_ = ((float)(w0 + p) - (DX)) * S - 0.5f;                   \
        float py_ = ((float)h - (DY)) * S - 0.5f;                          \
        float fx = floorf(px_), fy = floorf(py_);                          \
        int ix = (int)fx, iy = (int)fy;                                    \
        WX = px_ - fx; WY = py_ - fy;                                      \
        bool xv0 = (ix >= 0) & (ix < 96);                                  \
        bool xv1 = (ix >= -1) & (ix < 95);                                 \
        bool yv0 = (iy >= 0) & (iy < 96);                                  \
        bool yv1 = (iy >= -1) & (iy < 95);                                 \
        V00 = zv; V10 = zv; V01 = zv; V11 = zv;                            \
        if (yv0) {                                                         \
            const u16* rr = xb + (iy * 96 + ix) * 128;                     \
            if (xv0) V00 = *(const f16x8*)rr;                              \
            if (xv1) V10 = *(const f16x8*)(rr + 128);                      \
        }                                                                  \
        if (yv1) {                                                         \
            const u16* rr = xb + ((iy + 1) * 96 + ix) * 128;               \
            if (xv0) V01 = *(const f16x8*)rr;                              \
            if (xv1) V11 = *(const f16x8*)(rr + 128);                      \
        }                                                                  \
    }

    GISSUE(fdxc, fdyc, c00, c10, c01, c11, cwx, cwy);

    __syncthreads();   // xi/pvs staged (gather reads global, unaffected)

    // ---- phase 1: i2h 3x3 conv (x-ch 64 -> oc {wv,wv+4,wv+8}*16) ----
    f32x4 acc2[3][2] = {};
    {
        f16x8 aC[3], aN[3];
#pragma unroll
        for (int mi = 0; mi < 3; mi++)
            aC[mi] = Ai[(((wv + 4 * mi) * 9 + 0) * 2 + 0) * 64 + lane];
#pragma unroll 1
        for (int it = 0; it < 18; it++) {
            int tap = it >> 1, cib = it & 1;
            if (it < 17) {
                int tn = it + 1; int tapn = tn >> 1, cibn = tn & 1;
#pragma unroll
                for (int mi = 0; mi < 3; mi++)
                    aN[mi] = Ai[(((wv + 4 * mi) * 9 + tapn) * 2 + cibn) * 64 + lane];
            }
            int dy = tap / 3, dx = tap % 3;
            __builtin_amdgcn_s_setprio(1);
#pragma unroll
            for (int g = 0; g < 2; g++) {
                int px = g * 16 + n + dx;
                int cor = (cib * 4 + q) ^ (px & 7);
                f16x8 bb = *(const f16x8*)&xi[((dy * 34 + px) << 6) + (cor << 3)];
#pragma unroll
                for (int mi = 0; mi < 3; mi++)
                    acc2[mi][g] = __builtin_amdgcn_mfma_f32_16x16x32_f16(aC[mi], bb, acc2[mi][g], 0, 0, 0);
            }
            __builtin_amdgcn_s_setprio(0);
#pragma unroll
            for (int mi = 0; mi < 3; mi++) aC[mi] = aN[mi];
        }
    }

    // ---- phase 2: per-link gather + GEMM pipeline (R7 structure) ----
    f32x4 acc[3][2] = {};

#pragma unroll
    for (int l = 0; l < 13; l++) {
        float fdx2 = 0.f, fdy2 = 0.f;
        if (l + 2 < 13) { fdx2 = fl[(2 * l + 4) * 9216]; fdy2 = fl[(2 * l + 5) * 9216]; }
        if (l + 1 < 13) GISSUE(fdxn, fdyn, n00, n10, n01, n11, nwx, nwy);
        {
            float w00 = (1.f - cwx) * (1.f - cwy), w10 = cwx * (1.f - cwy);
            float w01 = (1.f - cwx) * cwy,         w11 = cwx * cwy;
            u16 res[8];
#pragma unroll
            for (int j = 0; j < 8; j++) {
                float v = w00 * (float)c00[j] + w10 * (float)c10[j]
                        + w01 * (float)c01[j] + w11 * (float)c11[j];
                res[j] = f2h(v);
            }
            uint4 o;
            o.x = res[0] | ((u32)res[1] << 16); o.y = res[2] | ((u32)res[3] << 16);
            o.z = res[4] | ((u32)res[5] << 16); o.w = res[6] | ((u32)res[7] << 16);
            *(uint4*)&gb[l & 1][p][sub * 8] = o;
        }
        __syncthreads();
        __builtin_amdgcn_s_setprio(1);
#pragma unroll
        for (int ksl = 0; ksl < 2; ksl++) {
            int ks = 2 * l + ksl;
            f16x8 b0 = *(const f16x8*)&gb[l & 1][n][ksl * 32 + q * 8];
            f16x8 b1 = *(const f16x8*)&gb[l & 1][16 + n][ksl * 32 + q * 8];
#pragma unroll
            for (int mi = 0; mi < 3; mi++) {
                f16x8 a = Ap[((wv + 4 * mi) * 26 + ks) * 64 + lane];
                acc[mi][0] = __builtin_amdgcn_mfma_f32_16x16x32_f16(a, b0, acc[mi][0], 0, 0, 0);
                acc[mi][1] = __builtin_amdgcn_mfma_f32_16x16x32_f16(a, b1, acc[mi][1], 0, 0, 0);
            }
        }
        __builtin_amdgcn_s_setprio(0);
        c00 = n00; c10 = n10; c01 = n01; c11 = n11; cwx = nwx; cwy = nwy;
        fdxc = fdxn; fdyc = fdyn; fdxn = fdx2; fdyn = fdy2;
    }
#undef GISSUE

    __syncthreads();   // gb dead; wst may overwrite it

    // ---- phase 3: gates fully in registers; stage nh -> wst ----
#pragma unroll
    for (int ni = 0; ni < 2; ni++)
#pragma unroll
        for (int r2 = 0; r2 < 4; r2++) {
            int ocg = wv * 16 + q * 4 + r2;      // 0..63
            int px = ni * 16 + n;
            float i0 = acc2[0][ni][r2] + biases[ocg];
            float i1 = acc2[1][ni][r2] + biases[64 + ocg];
            float i2 = acc2[2][ni][r2] + biases[128 + ocg];
            float h0 = acc[0][ni][r2] + biases[282 + ocg];
            float h1 = acc[1][ni][r2] + biases[282 + 64 + ocg];
            float h2 = acc[2][ni][r2] + biases[282 + 128 + ocg];
            int cor = (ocg >> 3) ^ (px & 7);
            float pv = h2f(pvs[(px << 6) + (cor << 3) + (ocg & 7)]);
            float rg = sigm(i0 + h0);
            float ug = sigm(i1 + h1);
            float nm = i2 + rg * h2;
            nm = (nm > 0.f) ? nm : NEG * nm;
            wst[ocg * 32 + px] = ug * pv + (1.f - ug) * nm;
        }
    __syncthreads();

    // ---- write-out: coalesced stores of both copies ----
#pragma unroll 1
    for (int j = 0; j < 8; j++) {
        int i = t + 256 * j;
        int pp = i & 31, cc = i >> 5;
        float nh = wst[cc * 32 + pp];
        int oidx = ((b * 64 + cc) * 96 + h) * 96 + w0 + pp;
        if (flg) {
            float* of = (float*)out;
            of[oidx] = nh;
            of[oidx + 2 * 4718592] = nh;
        } else {
            u16* ob16 = (u16*)out;
            u16 v = f2b(nh);
            ob16[oidx] = v;
            ob16[oidx + 2 * 4718592] = v;
        }
    }
}

// ---------------- K5: copy m passthrough (dtype-size aware) ----------------
__global__ void kcopym(const uint4* __restrict__ m, uint4* __restrict__ out,
                       const u32* __restrict__ flag)
{
    int flg = (int)flag[0];
    int n4 = flg ? 1179648 : 589824;   // uint4 chunks per tensor
    int stride = gridDim.x * 256;
    for (int i = blockIdx.x * 256 + threadIdx.x; i < n4; i += stride)
        out[n4 + i] = m[i];
}

extern "C" void kernel_launch(void* const* d_in, const int* in_sizes, int n_in,
                              void* d_out, int out_size, void* d_ws, size_t ws_size,
                              hipStream_t stream)
{
    const void* x     = d_in[0];
    const void* m     = d_in[1];
    const void* ph    = d_in[2];
    const void* w_i2h = d_in[3];
    const void* b_i2h = d_in[4];
    const void* w_i2f = d_in[5];
    const void* b_i2f = d_in[6];
    const void* w_h2f = d_in[7];
    const void* b_h2f = d_in[8];
    const void* w_fl  = d_in[9];
    const void* b_fl  = d_in[10];
    const void* w_ret = d_in[11];
    const void* b_ret = d_in[12];

    char* ws = (char*)d_ws;
    u32*    flag   = (u32*)  (ws + 0);
    u16*    wiA    = (u16*)  (ws + 64);
    u16*    wfA    = (u16*)  (ws + 221248);
    u16*    wlA    = (u16*)  (ws + 426048);
    u16*    wretA  = (u16*)  (ws + 477248);
    float*  biases = (float*)(ws + 796736);
    u16*    xph    = (u16*)  (ws + 798784);
    u16*    fT     = (u16*)  (ws + 47984704);
    float*  flows  = (float*)(ws + 52703296);
    if (ws_size < WS_NEED) return;  // diagnostic signature: absmax == max|ref|

    kdetect<<<1, 256, 0, stream>>>((const u16*)x, flag);
    kprep<<<624, 256, 0, stream>>>(w_i2h, w_i2f, w_h2f, w_fl, w_ret,
                                   b_i2h, b_i2f, b_h2f, b_fl, b_ret,
                                   wiA, wfA, wlA, wretA, biases, flag);
    kxph<<<dim3(96, 8), 256, 0, stream>>>(x, ph, xph, flag);
    k_flowfeat<<<dim3(1152), 256, 0, stream>>>(xph, wfA, biases, fT);
    k_flows<<<dim3(1152), 256, 0, stream>>>(fT, wlA, biases, flows);
    k_fused<<<dim3(2304), 256, 0, stream>>>(flows, xph, wiA, wretA, biases,
                                            d_out, flag);
    kcopym<<<2048, 256, 0, stream>>>((const uint4*)m, (uint4*)d_out, flag);
}

// Round 11
// 277.880 us; speedup vs baseline: 1.3915x; 1.0075x over previous
//
#include <hip/hip_runtime.h>
#include <hip/hip_bf16.h>
#include <hip/hip_fp16.h>

typedef unsigned short u16;
typedef unsigned int u32;
typedef __attribute__((ext_vector_type(8))) _Float16 f16x8;
typedef __attribute__((ext_vector_type(4))) float f32x4;

#define NEG 0.2f

__device__ __forceinline__ float bf2f(u16 u) {
    return __uint_as_float(((u32)u) << 16);
}
__device__ __forceinline__ u16 f2b(float f) {   // round-to-nearest-even f32->bf16
    u32 u = __float_as_uint(f);
    u32 r = (u + 0x7FFF + ((u >> 16) & 1)) >> 16;
    return (u16)r;
}
__device__ __forceinline__ u16 f2h(float f) {   // f32 -> f16 bits
    return __half_as_ushort(__float2half(f));
}
__device__ __forceinline__ float h2f(u16 u) {
    return __half2float(__ushort_as_half(u));
}
__device__ __forceinline__ float sigm(float x) {
    return 1.0f / (1.0f + __expf(-x));
}
__device__ __forceinline__ float ldin(const void* p, int idx, int flag) {
    if (flag) return ((const float*)p)[idx];
    return bf2f(((const u16*)p)[idx]);
}
__device__ __forceinline__ u16 ldin_h(const void* p, int idx, int flag) {  // -> f16 bits
    if (flag) return f2h(((const float*)p)[idx]);
    return f2h(bf2f(((const u16*)p)[idx]));
}

// ---------------- ws layout (bytes) ----------------
// flag    u32                        @ 0          (64)
// wiA     f16 [12][9][2][64][8]      @ 64         (221184)  i2h A-frags
// wfA     f16 [2][25][4][64][8]      @ 221248     (204800)  flowfeat A-frags
// wlA     f16 [2][25][64][8]         @ 426048     (51200)   flows A-frags
// wretA   f16 [12][26][64][8]        @ 477248     (319488)  ret A-frags
// biases  f32 [474]                  @ 796736     (2048)
// xph     f16 [8][96][96][128]       @ 798784     (18874368)  NHWC x||prev_h
// (i2hT region unused since R8 fusion)
// fT      f16 [8][96][96][32]        @ 47984704   (4718592)
// flows   f32 [8][26][96][96]        @ 52703296   (7667712)
// total: 60371008

#define WS_NEED 60371008u

// ---------------- K-1: dtype detect ----------------
__global__ void kdetect(const u16* __restrict__ x, u32* __restrict__ flag)
{
    __shared__ u32 mx[256];
    int t = threadIdx.x;
    u32 m = 0;
    for (int i = t; i < 8192; i += 256) {
        u32 e = ((u32)x[i] >> 7) & 0xFF;
        m = m > e ? m : e;
    }
    mx[t] = m;
    __syncthreads();
    for (int s = 128; s > 0; s >>= 1) {
        if (t < s) mx[t] = mx[t] > mx[t + s] ? mx[t] : mx[t + s];
        __syncthreads();
    }
    if (t == 0) flag[0] = (mx[0] > 0xC0) ? 1u : 0u;
}

// ---------------- K0a: weight repack -> MFMA A-fragments (f16) ----------------
__global__ void kprep(const void* __restrict__ w_i2h, const void* __restrict__ w_i2f,
                      const void* __restrict__ w_h2f, const void* __restrict__ w_fl,
                      const void* __restrict__ w_ret,
                      const void* __restrict__ b_i2h, const void* __restrict__ b_i2f,
                      const void* __restrict__ b_h2f, const void* __restrict__ b_fl,
                      const void* __restrict__ b_ret,
                      u16* __restrict__ wiA, u16* __restrict__ wfA,
                      u16* __restrict__ wlA, u16* __restrict__ wretA,
                      float* __restrict__ biases, const u32* __restrict__ flag)
{
    int flg = (int)flag[0];
    int i = blockIdx.x * 256 + threadIdx.x;
    // A-frag pattern: A[m=lane&15][k=(lane>>4)*8+j]  (validated R4)
    if (i < 110592) {                 // wiA [mt12][tap9][cib2][lane][j]
        int j = i & 7; int lane = (i >> 3) & 63; int rest = i >> 9;
        int cib = rest & 1; int rest2 = rest >> 1;
        int tap = rest2 % 9; int mt = rest2 / 9;
        int oc = mt * 16 + (lane & 15);
        int ci = cib * 32 + ((lane >> 4) << 3) + j;
        wiA[i] = ldin_h(w_i2h, (oc * 64 + ci) * 9 + tap, flg);
    }
    if (i < 102400) {                 // wfA [mt2][tap25][cib4][lane][j]
        int j = i & 7; int lane = (i >> 3) & 63; int rest = i >> 9;
        int cib = rest & 3; int rest2 = rest >> 2;
        int tap = rest2 % 25; int mt = rest2 / 25;
        int oc = mt * 16 + (lane & 15);
        int cip = cib * 32 + ((lane >> 4) << 3) + j;
        wfA[i] = (cip < 64) ? ldin_h(w_i2f, (oc * 64 + cip) * 25 + tap, flg)
                            : ldin_h(w_h2f, (oc * 64 + cip - 64) * 25 + tap, flg);
    }
    if (i < 25600) {                  // wlA [mt2][tap25][lane][j], oc>=26 -> 0
        int j = i & 7; int lane = (i >> 3) & 63; int rest = i >> 9;
        int tap = rest % 25; int mt = rest / 25;
        int oc = mt * 16 + (lane & 15);
        int ci = ((lane >> 4) << 3) + j;
        wlA[i] = (oc < 26) ? ldin_h(w_fl, (oc * 32 + ci) * 25 + tap, flg) : (u16)0;
    }
    if (i < 159744) {                 // wretA [mt12][ks26][lane][j]
        int j = i & 7; int l = (i >> 3) & 63; int rest = i >> 9;
        int ks = rest % 26; int mt = rest / 26;
        int o = mt * 16 + (l & 15);
        int k = ks * 32 + ((l >> 4) << 3) + j;
        wretA[i] = ldin_h(w_ret, o * 832 + k, flg);
    }
    if (i < 474) {
        float v;
        if (i < 192)      v = ldin(b_i2h, i, flg);
        else if (i < 224) v = ldin(b_i2f, i - 192, flg);
        else if (i < 256) v = ldin(b_h2f, i - 224, flg);
        else if (i < 282) v = ldin(b_fl, i - 256, flg);
        else              v = ldin(b_ret, i - 282, flg);
        biases[i] = v;
    }
}

// ---------------- K0b: x, prev_h (NCHW) -> xph NHWC f16 [B][H][W][128] ------
__global__ __launch_bounds__(256) void kxph(const void* __restrict__ x,
        const void* __restrict__ ph, u16* __restrict__ xph,
        const u32* __restrict__ flag)
{
    __shared__ __align__(16) u16 tile[64 * 104];
    int flg = (int)flag[0];
    int h = blockIdx.x, b = blockIdx.y;
    int t = threadIdx.x;
#pragma unroll 1
    for (int s = 0; s < 2; s++) {
        const void* src = s ? ph : x;
#pragma unroll 1
        for (int i = t; i < 768; i += 256) {      // 64 c x 12 w-chunks of 8
            int wc = i % 12, c = i / 12;
            int base = ((b * 64 + c) * 96 + h) * 96 + wc * 8;
            u16 r[8];
            if (flg) {
                const float* sp = (const float*)src + base;
                float4 f0 = *(const float4*)sp;
                float4 f1 = *(const float4*)(sp + 4);
                r[0] = f2h(f0.x); r[1] = f2h(f0.y); r[2] = f2h(f0.z); r[3] = f2h(f0.w);
                r[4] = f2h(f1.x); r[5] = f2h(f1.y); r[6] = f2h(f1.z); r[7] = f2h(f1.w);
            } else {
                const u16* sp = (const u16*)src + base;
                uint4 u = *(const uint4*)sp;
                r[0] = f2h(bf2f((u16)(u.x & 0xFFFF))); r[1] = f2h(bf2f((u16)(u.x >> 16)));
                r[2] = f2h(bf2f((u16)(u.y & 0xFFFF))); r[3] = f2h(bf2f((u16)(u.y >> 16)));
                r[4] = f2h(bf2f((u16)(u.z & 0xFFFF))); r[5] = f2h(bf2f((u16)(u.z >> 16)));
                r[6] = f2h(bf2f((u16)(u.w & 0xFFFF))); r[7] = f2h(bf2f((u16)(u.w >> 16)));
            }
            uint4 o;
            o.x = r[0] | ((u32)r[1] << 16); o.y = r[2] | ((u32)r[3] << 16);
            o.z = r[4] | ((u32)r[5] << 16); o.w = r[6] | ((u32)r[7] << 16);
            *(uint4*)&tile[c * 104 + wc * 8] = o;
        }
        __syncthreads();
#pragma unroll 1
        for (int i = t; i < 768; i += 256) {      // 96 w x 8 c-groups of 8
            int cg = i & 7, w = i >> 3;
            u16 v[8];
#pragma unroll
            for (int k = 0; k < 8; k++) v[k] = tile[(cg * 8 + k) * 104 + w];
            uint4 o;
            o.x = v[0] | ((u32)v[1] << 16); o.y = v[2] | ((u32)v[3] << 16);
            o.z = v[4] | ((u32)v[5] << 16); o.w = v[6] | ((u32)v[7] << 16);
            *(uint4*)&xph[(((b * 96 + h) * 96 + w) << 7) + s * 64 + cg * 8] = o;
        }
        __syncthreads();
    }
}

// ---------------- K2: flowfeat 5x5 conv (128 -> 32) via MFMA, out NHWC f16 --
__global__ __launch_bounds__(256) void k_flowfeat(const u16* __restrict__ xph,
        const u16* __restrict__ wfA, const float* __restrict__ biases,
        u16* __restrict__ fT)
{
    __shared__ __align__(16) u16 xl[8 * 20 * 136];   // 43520 B, x-stride 136
    int lin = blockIdx.x;            // 0..1151
    int b = lin & 7;
    int r = lin >> 3;                // 0..143
    int x0 = (r % 6) * 16, y0 = (r / 6) * 4;
    int t = threadIdx.x, lane = t & 63, wv = t >> 6;
    int n = lane & 15, quad = lane >> 4;

    for (int i = t; i < 2560; i += 256) {   // 160 pos x 16 chunks(16B)
        int co = i & 15; int pos = i >> 4; int xx = pos % 20; int yy = pos / 20;
        int gy = y0 + yy - 2, gx = x0 + xx - 2;
        uint4 v = make_uint4(0, 0, 0, 0);
        if (gy >= 0 && gy < 96 && gx >= 0 && gx < 96)
            v = *(const uint4*)&xph[((((b * 96 + gy) * 96 + gx)) << 7) + (co << 3)];
        *(uint4*)&xl[(yy * 20 + xx) * 136 + (co << 3)] = v;
    }
    __syncthreads();

    f32x4 acc0 = {}, acc1 = {};
    const f16x8* A = (const f16x8*)wfA;
    f16x8 bbC[4], a0C[4], a1C[4];
    {
        int rowb = (wv * 20 + n) * 136 + quad * 8;
#pragma unroll
        for (int cib = 0; cib < 4; cib++) {
            bbC[cib] = *(const f16x8*)&xl[rowb + cib * 32];
            a0C[cib] = A[cib * 64 + lane];
            a1C[cib] = A[(100 + cib) * 64 + lane];
        }
    }
#pragma unroll 1
    for (int tap = 0; tap < 25; tap++) {
        f16x8 bbN[4], a0N[4], a1N[4];
        if (tap < 24) {
            int tn = tap + 1;
            int dy = tn / 5, dx = tn % 5;
            int rowb = ((wv + dy) * 20 + n + dx) * 136 + quad * 8;
#pragma unroll
            for (int cib = 0; cib < 4; cib++) {
                bbN[cib] = *(const f16x8*)&xl[rowb + cib * 32];
                a0N[cib] = A[(tn * 4 + cib) * 64 + lane];
                a1N[cib] = A[((25 + tn) * 4 + cib) * 64 + lane];
            }
        }
#pragma unroll
        for (int cib = 0; cib < 4; cib++) {
            acc0 = __builtin_amdgcn_mfma_f32_16x16x32_f16(a0C[cib], bbC[cib], acc0, 0, 0, 0);
            acc1 = __builtin_amdgcn_mfma_f32_16x16x32_f16(a1C[cib], bbC[cib], acc1, 0, 0, 0);
        }
#pragma unroll
        for (int cib = 0; cib < 4; cib++) {
            bbC[cib] = bbN[cib]; a0C[cib] = a0N[cib]; a1C[cib] = a1N[cib];
        }
    }

    int base = (((b * 96 + y0 + wv) * 96 + x0 + n)) * 32 + quad * 4;
    {
        u16 p[4];
#pragma unroll
        for (int r2 = 0; r2 < 4; r2++) {
            int oc = quad * 4 + r2;
            float v = acc0[r2] + biases[192 + oc] + biases[224 + oc];
            v = (v > 0.f) ? v : NEG * v;
            p[r2] = f2h(v);
        }
        *(uint2*)&fT[base] = make_uint2(p[0] | ((u32)p[1] << 16), p[2] | ((u32)p[3] << 16));
#pragma unroll
        for (int r2 = 0; r2 < 4; r2++) {
            int oc = 16 + quad * 4 + r2;
            float v = acc1[r2] + biases[192 + oc] + biases[224 + oc];
            v = (v > 0.f) ? v : NEG * v;
            p[r2] = f2h(v);
        }
        *(uint2*)&fT[base + 16] = make_uint2(p[0] | ((u32)p[1] << 16), p[2] | ((u32)p[3] << 16));
    }
}

// ---------------- K3: flows 5x5 conv (32 -> 26) via MFMA, out NCHW f32 -------
// R11: ring-4 A-frag prefetch (full unroll -> compile-time ring indices).
// Cover per wait-point: 4 taps of {ds_read + 2 MFMA + interp} ~ 160-200 cyc
// vs L2 ~200 cyc. Tap order unchanged -> bitwise-identical output.
__global__ __launch_bounds__(256) void k_flows(const u16* __restrict__ fT,
        const u16* __restrict__ wlA, const float* __restrict__ biases,
        float* __restrict__ flows)
{
    __shared__ __align__(16) u16 xl[8 * 20 * 40];   // 12800 B, x-stride 40
    int lin = blockIdx.x;            // 0..1151
    int b = lin & 7;
    int r = lin >> 3;                // 0..143
    int x0 = (r % 6) * 16, y0 = (r / 6) * 4;
    int t = threadIdx.x, lane = t & 63, wv = t >> 6;
    int n = lane & 15, quad = lane >> 4;

    for (int i = t; i < 640; i += 256) {    // 160 pos x 4 chunks(16B)
        int co = i & 3; int pos = i >> 2; int xx = pos % 20; int yy = pos / 20;
        int gy = y0 + yy - 2, gx = x0 + xx - 2;
        uint4 v = make_uint4(0, 0, 0, 0);
        if (gy >= 0 && gy < 96 && gx >= 0 && gx < 96)
            v = *(const uint4*)&fT[((((b * 96 + gy) * 96 + gx)) << 5) + (co << 3)];
        *(uint4*)&xl[(yy * 20 + xx) * 40 + (co << 3)] = v;
    }
    __syncthreads();

    f32x4 acc0 = {}, acc1 = {};
    const f16x8* A = (const f16x8*)wlA;
    f16x8 a0r[4], a1r[4];
#pragma unroll
    for (int tp = 0; tp < 4; tp++) {
        a0r[tp] = A[tp * 64 + lane];
        a1r[tp] = A[(25 + tp) * 64 + lane];
    }
#pragma unroll
    for (int tap = 0; tap < 25; tap++) {
        int dy = tap / 5, dx = tap % 5;
        f16x8 bb = *(const f16x8*)&xl[((wv + dy) * 20 + n + dx) * 40 + quad * 8];
        f16x8 a0 = a0r[tap & 3];
        f16x8 a1 = a1r[tap & 3];
        if (tap + 4 < 25) {
            a0r[tap & 3] = A[(tap + 4) * 64 + lane];
            a1r[tap & 3] = A[(25 + tap + 4) * 64 + lane];
        }
        acc0 = __builtin_amdgcn_mfma_f32_16x16x32_f16(a0, bb, acc0, 0, 0, 0);
        acc1 = __builtin_amdgcn_mfma_f32_16x16x32_f16(a1, bb, acc1, 0, 0, 0);
    }

    int pix = (y0 + wv) * 96 + x0 + n;
#pragma unroll
    for (int r2 = 0; r2 < 4; r2++) {
        int oc = quad * 4 + r2;
        flows[(b * 26 + oc) * 9216 + pix] = acc0[r2] + biases[256 + oc];
        int oc1 = 16 + quad * 4 + r2;
        if (oc1 < 26)
            flows[(b * 26 + oc1) * 9216 + pix] = acc1[r2] + biases[256 + oc1];
    }
}

// ---------------- K4: i2h conv + warp + 1x1 conv + gates (fully fused) ------
// R11: phase-1 A-loads grouped PER TAP (6 frags current + 6 prefetch next):
// 9 wait-points (was 18), each covered by 12 MFMA + 4 ds_read (~130 cyc).
// A-state 48 VGPR; total ~88 < 128 budget (R6/R9 spill lesson respected).
// Per-accumulator summation order unchanged -> bitwise-identical.
__global__ __launch_bounds__(256, 4) void k_fused(const float* __restrict__ flows,
        const u16* __restrict__ xph, const u16* __restrict__ wiA,
        const u16* __restrict__ wretA, const float* __restrict__ biases,
        void* __restrict__ out, const u32* __restrict__ flag)
{
    __shared__ __align__(16) char sm[26368];
    u16* xi  = (u16*)sm;                                  // [3][34][64] swz, 13056 B
    u16* pvs = (u16*)(sm + 13056);                        // [32][64] swz, 4096 B
    u16 (*gb)[32][72] = (u16 (*)[32][72])(sm + 17152);    // [2][32][72], 9216 B
    float* wst = (float*)(sm + 17152);                    // [64][32] f32 overlay

    int flg = (int)flag[0];
    int lin = blockIdx.x;            // 0..2303
    int b = lin & 7;
    int r = lin >> 3;                // 0..287
    int w0 = (r % 3) * 32;
    int h = r / 3;
    int t = threadIdx.x;
    int lane = t & 63, wv = t >> 6;
    const float S = 96.f / 95.f;
    int hrow = h * 96 + w0;

    // ---- stage xi (3-row x-channel halo, px=gx-w0+1 in [0,34)) + pvs ----
#pragma unroll 1
    for (int i = t; i < 816; i += 256) {    // 102 pos x 8 chunks
        int co = i & 7; int pos = i >> 3;
        int px = pos % 34, dy = pos / 34;
        int gy = h + dy - 1, gx = w0 + px - 1;
        uint4 v = make_uint4(0, 0, 0, 0);
        if (gy >= 0 && gy < 96 && gx >= 0 && gx < 96)
            v = *(const uint4*)&xph[(((b * 96 + gy) * 96 + gx) << 7) + (co << 3)];
        *(uint4*)&xi[((dy * 34 + px) << 6) + ((co ^ (px & 7)) << 3)] = v;
    }
    {   // pvs: 32 px x 8 chunks of ph-channels at own row (1 chunk/thread)
        int co = t & 7; int px = t >> 3;
        uint4 v = *(const uint4*)&xph[(((b * 96 + h) * 96 + w0 + px) << 7) + 64 + (co << 3)];
        *(uint4*)&pvs[(px << 6) + ((co ^ (px & 7)) << 3)] = v;
    }

    int p = t >> 3, sub = t & 7;
    const float* fl = &flows[b * 26 * 9216 + hrow + p];
    const u16* xb = &xph[(b * 96) * 96 * 128 + 64 + sub * 8];

    int n = lane & 15, q = lane >> 4;
    const f16x8* Ap = (const f16x8*)wretA;
    const f16x8* Ai = (const f16x8*)wiA;
    const f16x8 zv = {};

    // flow loads for links 0,1 + link-0 gather issued BEFORE the i2h phase:
    // their latency hides under the 36 i2h MFMAs (R10 reorder).
    float fdxc = fl[0 * 9216], fdyc = fl[1 * 9216];
    float fdxn = fl[2 * 9216], fdyn = fl[3 * 9216];

    f16x8 c00, c10, c01, c11; float cwx, cwy;
    f16x8 n00, n10, n01, n11; float nwx, nwy;

#define GISSUE(DX, DY, V00, V10, V01, V11, WX, WY)                         \
    {                                                                      \
        float px_ = ((float)(w0 + p) - (DX)) * S - 0.5f;                   \
        float py_ = ((float)h - (DY)) * S - 0.5f;                          \
        float fx = floorf(px_), fy = floorf(py_);                          \
        int ix = (int)fx, iy = (int)fy;                                    \
        WX = px_ - fx; WY = py_ - fy;                                      \
        bool xv0 = (ix >= 0) & (ix < 96);                                  \
        bool xv1 = (ix >= -1) & (ix < 95);                                 \
        bool yv0 = (iy >= 0) & (iy < 96);                                  \
        bool yv1 = (iy >= -1) & (iy < 95);                                 \
        V00 = zv; V10 = zv; V01 = zv; V11 = zv;                            \
        if (yv0) {                                                         \
            const u16* rr = xb + (iy * 96 + ix) * 128;                     \
            if (xv0) V00 = *(const f16x8*)rr;                              \
            if (xv1) V10 = *(const f16x8*)(rr + 128);                      \
        }                                                                  \
        if (yv1) {                                                         \
            const u16* rr = xb + ((iy + 1) * 96 + ix) * 128;               \
            if (xv0) V01 = *(const f16x8*)rr;                              \
            if (xv1) V11 = *(const f16x8*)(rr + 128);                      \
        }                                                                  \
    }

    GISSUE(fdxc, fdyc, c00, c10, c01, c11, cwx, cwy);

    __syncthreads();   // xi/pvs staged (gather reads global, unaffected)

    // ---- phase 1: i2h 3x3 conv, tap-grouped A-prefetch ----
    f32x4 acc2[3][2] = {};
    {
        f16x8 aC[3][2], aN[3][2];    // [mi][cib]
#pragma unroll
        for (int mi = 0; mi < 3; mi++)
#pragma unroll
            for (int cib = 0; cib < 2; cib++)
                aC[mi][cib] = Ai[(((wv + 4 * mi) * 9 + 0) * 2 + cib) * 64 + lane];
#pragma unroll 1
        for (int tap = 0; tap < 9; tap++) {
            if (tap < 8) {
#pragma unroll
                for (int mi = 0; mi < 3; mi++)
#pragma unroll
                    for (int cib = 0; cib < 2; cib++)
                        aN[mi][cib] = Ai[(((wv + 4 * mi) * 9 + tap + 1) * 2 + cib) * 64 + lane];
            }
            int dy = tap / 3, dx = tap % 3;
            __builtin_amdgcn_s_setprio(1);
#pragma unroll
            for (int cib = 0; cib < 2; cib++)
#pragma unroll
                for (int g = 0; g < 2; g++) {
                    int px = g * 16 + n + dx;
                    int cor = (cib * 4 + q) ^ (px & 7);
                    f16x8 bb = *(const f16x8*)&xi[((dy * 34 + px) << 6) + (cor << 3)];
#pragma unroll
                    for (int mi = 0; mi < 3; mi++)
                        acc2[mi][g] = __builtin_amdgcn_mfma_f32_16x16x32_f16(aC[mi][cib], bb, acc2[mi][g], 0, 0, 0);
                }
            __builtin_amdgcn_s_setprio(0);
#pragma unroll
            for (int mi = 0; mi < 3; mi++)
#pragma unroll
                for (int cib = 0; cib < 2; cib++)
                    aC[mi][cib] = aN[mi][cib];
        }
    }

    // ---- phase 2: per-link gather + GEMM pipeline (R7 structure) ----
    f32x4 acc[3][2] = {};

#pragma unroll
    for (int l = 0; l < 13; l++) {
        float fdx2 = 0.f, fdy2 = 0.f;
        if (l + 2 < 13) { fdx2 = fl[(2 * l + 4) * 9216]; fdy2 = fl[(2 * l + 5) * 9216]; }
        if (l + 1 < 13) GISSUE(fdxn, fdyn, n00, n10, n01, n11, nwx, nwy);
        {
            float w00 = (1.f - cwx) * (1.f - cwy), w10 = cwx * (1.f - cwy);
            float w01 = (1.f - cwx) * cwy,         w11 = cwx * cwy;
            u16 res[8];
#pragma unroll
            for (int j = 0; j < 8; j++) {
                float v = w00 * (float)c00[j] + w10 * (float)c10[j]
                        + w01 * (float)c01[j] + w11 * (float)c11[j];
                res[j] = f2h(v);
            }
            uint4 o;
            o.x = res[0] | ((u32)res[1] << 16); o.y = res[2] | ((u32)res[3] << 16);
            o.z = res[4] | ((u32)res[5] << 16); o.w = res[6] | ((u32)res[7] << 16);
            *(uint4*)&gb[l & 1][p][sub * 8] = o;
        }
        __syncthreads();
        __builtin_amdgcn_s_setprio(1);
#pragma unroll
        for (int ksl = 0; ksl < 2; ksl++) {
            int ks = 2 * l + ksl;
            f16x8 b0 = *(const f16x8*)&gb[l & 1][n][ksl * 32 + q * 8];
            f16x8 b1 = *(const f16x8*)&gb[l & 1][16 + n][ksl * 32 + q * 8];
#pragma unroll
            for (int mi = 0; mi < 3; mi++) {
                f16x8 a = Ap[((wv + 4 * mi) * 26 + ks) * 64 + lane];
                acc[mi][0] = __builtin_amdgcn_mfma_f32_16x16x32_f16(a, b0, acc[mi][0], 0, 0, 0);
                acc[mi][1] = __builtin_amdgcn_mfma_f32_16x16x32_f16(a, b1, acc[mi][1], 0, 0, 0);
            }
        }
        __builtin_amdgcn_s_setprio(0);
        c00 = n00; c10 = n10; c01 = n01; c11 = n11; cwx = nwx; cwy = nwy;
        fdxc = fdxn; fdyc = fdyn; fdxn = fdx2; fdyn = fdy2;
    }
#undef GISSUE

    __syncthreads();   // gb dead; wst may overwrite it

    // ---- phase 3: gates fully in registers; stage nh -> wst ----
#pragma unroll
    for (int ni = 0; ni < 2; ni++)
#pragma unroll
        for (int r2 = 0; r2 < 4; r2++) {
            int ocg = wv * 16 + q * 4 + r2;      // 0..63
            int px = ni * 16 + n;
            float i0 = acc2[0][ni][r2] + biases[ocg];
            float i1 = acc2[1][ni][r2] + biases[64 + ocg];
            float i2 = acc2[2][ni][r2] + biases[128 + ocg];
            float h0 = acc[0][ni][r2] + biases[282 + ocg];
            float h1 = acc[1][ni][r2] + biases[282 + 64 + ocg];
            float h2 = acc[2][ni][r2] + biases[282 + 128 + ocg];
            int cor = (ocg >> 3) ^ (px & 7);
            float pv = h2f(pvs[(px << 6) + (cor << 3) + (ocg & 7)]);
            float rg = sigm(i0 + h0);
            float ug = sigm(i1 + h1);
            float nm = i2 + rg * h2;
            nm = (nm > 0.f) ? nm : NEG * nm;
            wst[ocg * 32 + px] = ug * pv + (1.f - ug) * nm;
        }
    __syncthreads();

    // ---- write-out: coalesced stores of both copies ----
#pragma unroll 1
    for (int j = 0; j < 8; j++) {
        int i = t + 256 * j;
        int pp = i & 31, cc = i >> 5;
        float nh = wst[cc * 32 + pp];
        int oidx = ((b * 64 + cc) * 96 + h) * 96 + w0 + pp;
        if (flg) {
            float* of = (float*)out;
            of[oidx] = nh;
            of[oidx + 2 * 4718592] = nh;
        } else {
            u16* ob16 = (u16*)out;
            u16 v = f2b(nh);
            ob16[oidx] = v;
            ob16[oidx + 2 * 4718592] = v;
        }
    }
}

// ---------------- K5: copy m passthrough (dtype-size aware) ----------------
__global__ void kcopym(const uint4* __restrict__ m, uint4* __restrict__ out,
                       const u32* __restrict__ flag)
{
    int flg = (int)flag[0];
    int n4 = flg ? 1179648 : 589824;   // uint4 chunks per tensor
    int stride = gridDim.x * 256;
    for (int i = blockIdx.x * 256 + threadIdx.x; i < n4; i += stride)
        out[n4 + i] = m[i];
}

extern "C" void kernel_launch(void* const* d_in, const int* in_sizes, int n_in,
                              void* d_out, int out_size, void* d_ws, size_t ws_size,
                              hipStream_t stream)
{
    const void* x     = d_in[0];
    const void* m     = d_in[1];
    const void* ph    = d_in[2];
    const void* w_i2h = d_in[3];
    const void* b_i2h = d_in[4];
    const void* w_i2f = d_in[5];
    const void* b_i2f = d_in[6];
    const void* w_h2f = d_in[7];
    const void* b_h2f = d_in[8];
    const void* w_fl  = d_in[9];
    const void* b_fl  = d_in[10];
    const void* w_ret = d_in[11];
    const void* b_ret = d_in[12];

    char* ws = (char*)d_ws;
    u32*    flag   = (u32*)  (ws + 0);
    u16*    wiA    = (u16*)  (ws + 64);
    u16*    wfA    = (u16*)  (ws + 221248);
    u16*    wlA    = (u16*)  (ws + 426048);
    u16*    wretA  = (u16*)  (ws + 477248);
    float*  biases = (float*)(ws + 796736);
    u16*    xph    = (u16*)  (ws + 798784);
    u16*    fT     = (u16*)  (ws + 47984704);
    float*  flows  = (float*)(ws + 52703296);
    if (ws_size < WS_NEED) return;  // diagnostic signature: absmax == max|ref|

    kdetect<<<1, 256, 0, stream>>>((const u16*)x, flag);
    kprep<<<624, 256, 0, stream>>>(w_i2h, w_i2f, w_h2f, w_fl, w_ret,
                                   b_i2h, b_i2f, b_h2f, b_fl, b_ret,
                                   wiA, wfA, wlA, wretA, biases, flag);
    kxph<<<dim3(96, 8), 256, 0, stream>>>(x, ph, xph, flag);
    k_flowfeat<<<dim3(1152), 256, 0, stream>>>(xph, wfA, biases, fT);
    k_flows<<<dim3(1152), 256, 0, stream>>>(fT, wlA, biases, flows);
    k_fused<<<dim3(2304), 256, 0, stream>>>(flows, xph, wiA, wretA, biases,
                                            d_out, flag);
    kcopym<<<2048, 256, 0, stream>>>((const uint4*)m, (uint4*)d_out, flag);
}